// Round 6
// baseline (3020.390 us; speedup 1.0000x reference)
//
#include <hip/hip_runtime.h>
#include <stdint.h>
#include <math.h>

// ---------------------------------------------------------------------------
// PathIntegration: h = relu(actions@w1+b1); trans = (h@w2+b2) -> [B,T,D,D]
// s_{t+1} = l2norm(relu(s_t @ trans_t)); output ys[B,T,D] (f32)
// B=32 T=512 A=64 H=256 D=128
// Round 6: rec chain b split over 4 parts (blocks b+32p, same XCD under
// round-robin), each streaming 8 KB/step (cols p*32..+32) with a pinned
// 4-deep asm ring (uniform vmcnt(6) via wrapped prefetch). Per-step v
// exchange via agent-scope atomics in ws (parity slots, seq tag = step+1),
// handled by a dedicated comm wave so its release vmcnt(0) never drains
// the compute waves' rings. grid=256 @ 1 block/CU -> all blocks resident.
// GEMM: 128 persistent blocks, 256x256 tiles (chunk c+1), trans dbuffered.
// ---------------------------------------------------------------------------

typedef _Float16 f16x8 __attribute__((ext_vector_type(8)));
typedef _Float16 f16x4 __attribute__((ext_vector_type(4)));
typedef _Float16 f16x2 __attribute__((ext_vector_type(2)));
typedef float    f32x4 __attribute__((ext_vector_type(4)));

#define B_  32
#define T_  512
#define A_  64
#define H_  256
#define D_  128
#define N_  (D_ * D_)      // 16384
#define M_  (B_ * T_)      // 16384

union PkU { unsigned long long u; f16x4 h4; f16x2 h2[2]; _Float16 h[4]; };

__device__ inline void async_ld16(const void* g, void* l) {
  __builtin_amdgcn_global_load_lds(
      (__attribute__((address_space(1))) void*)g,
      (__attribute__((address_space(3))) void*)l, 16, 0, 0);
}

// pinned 32B load: LO,HI <- P, P+16B
#define LD2(LO, HI, P)                                                       \
  asm volatile("global_load_dwordx4 %0, %2, off\n\t"                         \
               "global_load_dwordx4 %1, %2, off offset:16"                   \
               : "=v"(LO), "=v"(HI) : "v"(P) : "memory")
// steady-state wait: 8 outstanding, oldest 2 (this slot) must land
#define RW6(LO, HI)                                                          \
  asm volatile("s_waitcnt vmcnt(6)" : "+v"(LO), "+v"(HI) :: "memory")

// ---------------- w2 cast + transpose + PERMUTE ------------------------------
// w2 [K=256][N=16384] f32 -> w2t [n'][K] fp16 with n' = (j<<7)|i for n=(i<<7)|j
__global__ __launch_bounds__(256) void w2cast_kernel(const float* __restrict__ w2,
                                                     _Float16* __restrict__ w2t) {
  __shared__ float tile[64][65];
  const int t = threadIdx.x;
  const int n0 = blockIdx.x * 64, k0 = blockIdx.y * 64;
  const int nn = t & 63, kg = t >> 6;
  #pragma unroll
  for (int r = 0; r < 16; ++r) {
    int k = kg * 16 + r;
    tile[k][nn] = w2[(size_t)(k0 + k) * N_ + n0 + nn];
  }
  __syncthreads();
  const int kk = t & 63, ng = t >> 6;
  #pragma unroll
  for (int r = 0; r < 16; ++r) {
    int n = ng * 16 + r;
    int ngl = n0 + n;
    int nperm = ((ngl & 127) << 7) | (ngl >> 7);
    w2t[(size_t)nperm * H_ + k0 + kk] = (_Float16)tile[kk][n];
  }
}

// ---------------- h = relu(actions@w1+b1) fp16 [16384][256] ------------------
__global__ __launch_bounds__(256) void h_kernel(const float* __restrict__ actions,
                                                const float* __restrict__ w1,
                                                const float* __restrict__ b1,
                                                _Float16* __restrict__ h16) {
  __shared__ float w1s[32 * 256];
  __shared__ float acts[32 * 64];
  const int t = threadIdx.x;
  const size_t row0 = (size_t)blockIdx.x * 32;

  #pragma unroll
  for (int i = 0; i < 8; ++i) acts[t + i * 256] = actions[row0 * A_ + t + i * 256];

  float acc[32];
  float bj = b1[t];
  #pragma unroll
  for (int r = 0; r < 32; ++r) acc[r] = bj;

  for (int half = 0; half < 2; ++half) {
    __syncthreads();
    #pragma unroll
    for (int i = 0; i < 32; ++i) w1s[t + i * 256] = w1[half * 32 * 256 + t + i * 256];
    __syncthreads();
    #pragma unroll
    for (int r = 0; r < 32; ++r) {
      float a = acc[r];
      #pragma unroll
      for (int k = 0; k < 32; ++k)
        a += acts[r * 64 + half * 32 + k] * w1s[k * 256 + t];
      acc[r] = a;
    }
  }
  #pragma unroll
  for (int r = 0; r < 32; ++r)
    h16[(row0 + r) * H_ + t] = (_Float16)fmaxf(acc[r], 0.f);
}

// ---------------- fused: rec parts blocks 0..127, gemm blocks 128..255 -------
__global__ __launch_bounds__(512, 2) void fused_kernel(
    const _Float16* __restrict__ h16, const _Float16* __restrict__ w2t,
    const float* __restrict__ b2, _Float16* __restrict__ tbuf0,
    _Float16* __restrict__ tbuf1, const float* __restrict__ init_s,
    float* __restrict__ out, unsigned long long* __restrict__ xch,
    int Tc, int tcs, int c, int nch) {

  __shared__ __align__(16) char smem[33024];
  const int tid  = threadIdx.x;
  const int lane = tid & 63;
  const int w    = tid >> 6;

  auto ldsbar = [&]() {
    asm volatile("s_waitcnt lgkmcnt(0)" ::: "memory");
    __builtin_amdgcn_s_barrier();
  };

  if (blockIdx.x < 128) {
    // ======================= recurrence part ================================
    if (c < 0) return;
    const _Float16* trans = (c & 1) ? tbuf1 : tbuf0;
    const int b  = blockIdx.x & 31;        // chain
    const int p  = blockIdx.x >> 5;        // part 0..3 (cols p*32..p*32+31)
    const int t0 = c * Tc;

    _Float16* s_sh = (_Float16*)smem;           // 128 f16 (256 B)
    float*    vsh  = (float*)(smem + 512);      // 32 f32 (part's v) / init red

    // ---- init s_0 locally (identical in all parts) ----
    if (tid < 128) {
      float v0 = (t0 == 0) ? init_s[tid] : out[((size_t)b * T_ + t0 - 1) * D_ + tid];
      float ss = v0 * v0;
      #pragma unroll
      for (int off = 32; off > 0; off >>= 1) ss += __shfl_xor(ss, off);
      if (lane == 0) vsh[w] = ss;
      ldsbar();
      float inv = 1.f / fmaxf(sqrtf(vsh[0] + vsh[1]), 1e-12f);
      s_sh[tid] = (_Float16)(v0 * inv);
      ldsbar();
    } else {
      ldsbar(); ldsbar();
    }

    // compute-wave geometry (waves 0..3): 8 cols/wave, 16 i per lane
    const int cc  = lane >> 3;             // 0..7 col within wave
    const int ii2 = lane & 7;              // i-group: i in [ii2*16, ii2*16+16)
    const int jloc = w * 8 + cc;           // 0..31 (valid for w<4)
    const _Float16* Tbl = trans + (size_t)b * Tc * N_
                        + (size_t)(p * 32 + jloc) * 128 + ii2 * 16;

    f16x8 rlo[4], rhi[4];
    if (w < 4) {   // preload ring: slots 0..3 = steps 0..3 (8 loads outstanding)
      LD2(rlo[0], rhi[0], Tbl + 0 * (size_t)N_);
      LD2(rlo[1], rhi[1], Tbl + 1 * (size_t)N_);
      LD2(rlo[2], rhi[2], Tbl + 2 * (size_t)N_);
      LD2(rlo[3], rhi[3], Tbl + 3 * (size_t)N_);
    }

    // exchange slots: ((b*4+k)*2+par)*16 u64; payload [0..7], seq at [8]
    unsigned long long* xbase = xch + (size_t)(b * 4) * 2 * 16;

#define CSTEP(U)                                                             \
    {                                                                        \
      const int tt = tt0 + (U);                                              \
      if (w < 4) {                                                           \
        RW6(rlo[U], rhi[U]);                                                 \
        f16x8 sv0 = *(const f16x8*)(s_sh + ii2 * 16);                        \
        f16x8 sv1 = *(const f16x8*)(s_sh + ii2 * 16 + 8);                    \
        const f16x2* tp0 = (const f16x2*)&rlo[U];                            \
        const f16x2* tp1 = (const f16x2*)&rhi[U];                            \
        const f16x2* sp0 = (const f16x2*)&sv0;                               \
        const f16x2* sp1 = (const f16x2*)&sv1;                               \
        float y = 0.f;                                                       \
        y = __builtin_amdgcn_fdot2(tp0[0], sp0[0], y, false);                \
        y = __builtin_amdgcn_fdot2(tp0[1], sp0[1], y, false);                \
        y = __builtin_amdgcn_fdot2(tp0[2], sp0[2], y, false);                \
        y = __builtin_amdgcn_fdot2(tp0[3], sp0[3], y, false);                \
        y = __builtin_amdgcn_fdot2(tp1[0], sp1[0], y, false);                \
        y = __builtin_amdgcn_fdot2(tp1[1], sp1[1], y, false);                \
        y = __builtin_amdgcn_fdot2(tp1[2], sp1[2], y, false);                \
        y = __builtin_amdgcn_fdot2(tp1[3], sp1[3], y, false);                \
        int nt_ = tt + 4; if (nt_ >= Tc) nt_ -= Tc;                          \
        LD2(rlo[U], rhi[U], Tbl + (size_t)nt_ * N_);                         \
        y += __shfl_xor(y, 1);                                               \
        y += __shfl_xor(y, 2);                                               \
        y += __shfl_xor(y, 4);                                               \
        if (ii2 == 0) vsh[jloc] = fmaxf(y, 0.f);                             \
      }                                                                      \
      ldsbar();                                                              \
      if (w == 4) {                                                          \
        const int gt = t0 + tt;                                              \
        const unsigned long long tag = (unsigned long long)(gt + 1);         \
        const int par = (int)(tag & 1);                                      \
        unsigned long long* myslot = xbase + (size_t)(p * 2 + par) * 16;     \
        if (lane < 8) {                                                      \
          float4 v4 = *(const float4*)(vsh + lane * 4);                      \
          PkU pk;                                                            \
          pk.h[0] = (_Float16)v4.x; pk.h[1] = (_Float16)v4.y;                \
          pk.h[2] = (_Float16)v4.z; pk.h[3] = (_Float16)v4.w;                \
          __hip_atomic_store(myslot + lane, pk.u, __ATOMIC_RELAXED,          \
                             __HIP_MEMORY_SCOPE_AGENT);                      \
        }                                                                    \
        if (lane == 0)                                                       \
          __hip_atomic_store(myslot + 8, tag, __ATOMIC_RELEASE,              \
                             __HIP_MEMORY_SCOPE_AGENT);                      \
        float ssl = 0.f; PkU pv; pv.u = 0;                                   \
        if (lane < 32) {                                                     \
          const int k = lane >> 3, widx = lane & 7;                          \
          unsigned long long* kslot = xbase + (size_t)(k * 2 + par) * 16;    \
          unsigned long long sv; int it = 0;                                 \
          do {                                                               \
            sv = __hip_atomic_load(kslot + 8, __ATOMIC_ACQUIRE,              \
                                   __HIP_MEMORY_SCOPE_AGENT);                \
          } while (sv != tag && ++it < (1 << 22));                           \
          pv.u = __hip_atomic_load(kslot + widx, __ATOMIC_RELAXED,           \
                                   __HIP_MEMORY_SCOPE_AGENT);                \
          ssl = __builtin_amdgcn_fdot2(pv.h2[0], pv.h2[0], 0.f, false);      \
          ssl = __builtin_amdgcn_fdot2(pv.h2[1], pv.h2[1], ssl, false);      \
        }                                                                    \
        ssl += __shfl_xor(ssl, 1);                                           \
        ssl += __shfl_xor(ssl, 2);                                           \
        ssl += __shfl_xor(ssl, 4);                                           \
        ssl += __shfl_xor(ssl, 8);                                           \
        ssl += __shfl_xor(ssl, 16);                                          \
        float inv = 1.f / fmaxf(sqrtf(ssl), 1e-12f);                         \
        if (lane < 32) {                                                     \
          const int k = lane >> 3, widx = lane & 7;                          \
          float x0 = (float)pv.h[0] * inv, x1 = (float)pv.h[1] * inv;        \
          float x2 = (float)pv.h[2] * inv, x3 = (float)pv.h[3] * inv;        \
          f16x4 sq; sq[0] = (_Float16)x0; sq[1] = (_Float16)x1;              \
          sq[2] = (_Float16)x2; sq[3] = (_Float16)x3;                        \
          *(f16x4*)(s_sh + k * 32 + widx * 4) = sq;                          \
          if (k == p) {                                                      \
            float4 o; o.x = x0; o.y = x1; o.z = x2; o.w = x3;                \
            *(float4*)(out + ((size_t)b * T_ + gt) * D_ + p * 32 + widx * 4) = o; \
          }                                                                  \
        }                                                                    \
      }                                                                      \
      ldsbar();                                                              \
    }

    for (int tt0 = 0; tt0 < Tc; tt0 += 4) {
      CSTEP(0) CSTEP(1) CSTEP(2) CSTEP(3)
    }
#undef CSTEP
    // drain compute waves' wrapped prefetches before exit
    if (w < 4) asm volatile("s_waitcnt vmcnt(0)" ::: "memory");
  } else {
    // ======================= persistent gemm (chunk c+1) ====================
    const int g = c + 1;
    if (g >= nch) return;
    _Float16* trans = (g & 1) ? tbuf1 : tbuf0;
    const int t0g = g * Tc;

    _Float16* smA = (_Float16*)smem;            // 256x32 fp16 = 16 KB
    _Float16* smB = (_Float16*)(smem + 16384);  // 16 KB

    const int wm = w >> 2, wn = w & 3;          // 2x4 wave grid: 128m x 64n
    const int fm = lane & 15, fq = lane >> 4;
    const f32x4 zero = {0.f, 0.f, 0.f, 0.f};

    // staging: 1024 chunks of 16B per tile operand; thread does 2 (s=0,1)
    const int cA0 = tid, cA1 = tid + 512;
    const int rA0 = cA0 >> 2, kA0 = cA0 & 3;
    const int rA1 = cA1 >> 2, kA1 = cA1 & 3;

    const int mtiles = (B_ * Tc) >> 8;
    const int ntot = mtiles * 64;
    for (int tile = (int)blockIdx.x - 128; tile < ntot; tile += 128) {
      const int bn = tile & 63;
      const int bm = tile >> 6;

      // A row decode (chunk-local row -> h16 global row)
      const int mc0 = bm * 256 + rA0, mc1 = bm * 256 + rA1;
      const int bb0 = mc0 >> tcs, bb1 = mc1 >> tcs;
      const _Float16* gA0 = h16 + ((size_t)bb0 * T_ + t0g + (mc0 & (Tc - 1))) * H_ + kA0 * 8;
      const _Float16* gA1 = h16 + ((size_t)bb1 * T_ + t0g + (mc1 & (Tc - 1))) * H_ + kA1 * 8;
      const _Float16* gB0 = w2t + ((size_t)bn * 256 + rA0) * H_ + kA0 * 8;
      const _Float16* gB1 = w2t + ((size_t)bn * 256 + rA1) * H_ + kA1 * 8;
      _Float16* lA0 = &smA[cA0 * 8];
      _Float16* lA1 = &smA[cA1 * 8];
      _Float16* lB0 = &smB[cA0 * 8];
      _Float16* lB1 = &smB[cA1 * 8];

      f32x4 acc[8][4];
      #pragma unroll
      for (int i = 0; i < 8; ++i)
        #pragma unroll
        for (int j = 0; j < 4; ++j) acc[i][j] = zero;

      for (int kt = 0; kt < H_ / 32; ++kt) {
        __syncthreads();
        async_ld16(gA0 + kt * 32, lA0);
        async_ld16(gA1 + kt * 32, lA1);
        async_ld16(gB0 + kt * 32, lB0);
        async_ld16(gB1 + kt * 32, lB1);
        __syncthreads();
        f16x8 af[8], bf[4];
        #pragma unroll
        for (int mt = 0; mt < 8; ++mt)
          af[mt] = *(const f16x8*)&smA[(wm * 128 + mt * 16 + fm) * 32 + fq * 8];
        #pragma unroll
        for (int nt = 0; nt < 4; ++nt)
          bf[nt] = *(const f16x8*)&smB[(wn * 64 + nt * 16 + fm) * 32 + fq * 8];
        #pragma unroll
        for (int mt = 0; mt < 8; ++mt)
          #pragma unroll
          for (int nt = 0; nt < 4; ++nt)
            acc[mt][nt] = __builtin_amdgcn_mfma_f32_16x16x32_f16(af[mt], bf[nt], acc[mt][nt], 0, 0, 0);
      }

      // epilogue: col is PERMUTED n'=(j<<7)|i; bias needs orig n
      #pragma unroll
      for (int nt = 0; nt < 4; ++nt) {
        int col = bn * 256 + wn * 64 + nt * 16 + fm;
        int norig = ((col & 127) << 7) | (col >> 7);
        float bias = b2[norig];
        #pragma unroll
        for (int mt = 0; mt < 8; ++mt) {
          #pragma unroll
          for (int r = 0; r < 4; ++r) {
            long row = bm * 256 + wm * 128 + mt * 16 + fq * 4 + r;
            trans[row * (long)N_ + col] = (_Float16)(acc[mt][nt][r] + bias);
          }
        }
      }
      __syncthreads();
    }
  }
}

// ---------------------------------------------------------------------------
extern "C" void kernel_launch(void* const* d_in, const int* in_sizes, int n_in,
                              void* d_out, int out_size, void* d_ws, size_t ws_size,
                              hipStream_t stream) {
  const float* actions = (const float*)d_in[0];   // [32,512,64]
  const float* init_s  = (const float*)d_in[1];   // [128]
  const float* w1      = (const float*)d_in[2];   // [64,256]
  const float* b1      = (const float*)d_in[3];   // [256]
  const float* w2      = (const float*)d_in[4];   // [256,16384]
  const float* b2      = (const float*)d_in[5];   // [16384]
  float* out = (float*)d_out;                     // [32,512,128]

  uint8_t* ws = (uint8_t*)d_ws;
  _Float16* w2t = (_Float16*)ws;                          // 8 MB (permuted rows)
  _Float16* h16 = (_Float16*)(ws + ((size_t)8 << 20));    // 8 MB
  const size_t trans_off = (size_t)16 << 20;

  // largest Tc whose double-buffered trans + 32KB exchange fits
  int Tc = 16;
  const int cands[3] = {64, 32, 16};
  for (int i = 0; i < 3; ++i) {
    if (trans_off + 2 * ((size_t)cands[i] << 20) + 65536 <= ws_size) { Tc = cands[i]; break; }
  }
  const int tcs = __builtin_ctz(Tc);
  _Float16* tbuf0 = (_Float16*)(ws + trans_off);
  _Float16* tbuf1 = (_Float16*)(ws + trans_off + ((size_t)Tc << 20));
  unsigned long long* xch =
      (unsigned long long*)(ws + trans_off + 2 * ((size_t)Tc << 20));

  w2cast_kernel<<<dim3(N_ / 64, 4), 256, 0, stream>>>(w2, w2t);
  h_kernel<<<M_ / 32, 256, 0, stream>>>(actions, w1, b1, h16);

  const int nch = T_ / Tc;
  for (int c = -1; c < nch; ++c) {
    fused_kernel<<<256, 512, 0, stream>>>(
        h16, w2t, b2, tbuf0, tbuf1, init_s, out, xch, Tc, tcs, c, nch);
  }
}

// Round 7
// 524.211 us; speedup vs baseline: 5.7618x; 5.7618x over previous
//
#include <hip/hip_runtime.h>
#include <stdint.h>
#include <math.h>

// ---------------------------------------------------------------------------
// PathIntegration: h = relu(actions@w1+b1); trans = (h@w2+b2) -> [B,T,D,D]
// s_{t+1} = l2norm(relu(s_t @ trans_t)); output ys[B,T,D] (f32)
// B=32 T=512 A=64 H=256 D=128
// Round 7: rec streams T via global_load_lds DMA ring (depth 2, 48 KB LDS,
// 3 KB/wave/step) + one pinned register frag (1 KB/wave/step), all K-loop
// LDS/global ops in inline asm with manual vmcnt schedule (uniform vmcnt(6)),
// one s_barrier/step, ||s||^2 via MFMA(A,A) chain (no cross-lane ops).
// trans global layout is MFMA-fragment-direct via the w2 permutation.
// Grid = 256 exactly -> 1 block/CU -> no gemm/rec CU sharing.
// ---------------------------------------------------------------------------

typedef _Float16 f16x8 __attribute__((ext_vector_type(8)));
typedef float    f32x4 __attribute__((ext_vector_type(4)));

#define B_  32
#define T_  512
#define A_  64
#define H_  256
#define D_  128
#define N_  (D_ * D_)      // 16384
#define M_  (B_ * T_)      // 16384

__device__ inline void glds(const void* g, void* l) {
  __builtin_amdgcn_global_load_lds(
      (__attribute__((address_space(1))) void*)g,
      (__attribute__((address_space(3))) void*)l, 16, 0, 0);
}

// ---------------- w2 cast + transpose + fragment-direct PERMUTE --------------
// orig col n of w2 -> T entry (i=n>>7, j=n&127). New position (elements):
// p = (j>>4)<<11 | (i>>5)<<9 | ((i>>3)&3)<<7 | (j&15)<<3 | (i&7)
// so per (b,t) the 32 KB step-slab is laid out wave-major, frag-major,
// lane-direct: byte ofs = w*4096 + f*1024 + q*256 + n16*16 + r*2.
__global__ __launch_bounds__(256) void w2cast_kernel(const float* __restrict__ w2,
                                                     _Float16* __restrict__ w2t) {
  __shared__ float tile[64][65];
  const int t = threadIdx.x;
  const int n0 = blockIdx.x * 64, k0 = blockIdx.y * 64;
  const int nn = t & 63, kg = t >> 6;
  #pragma unroll
  for (int r = 0; r < 16; ++r) {
    int k = kg * 16 + r;
    tile[k][nn] = w2[(size_t)(k0 + k) * N_ + n0 + nn];
  }
  __syncthreads();
  const int kk = t & 63, ng = t >> 6;
  #pragma unroll
  for (int r = 0; r < 16; ++r) {
    int n = ng * 16 + r;
    int ngl = n0 + n;
    int i = ngl >> 7, j = ngl & 127;
    int p = ((j >> 4) << 11) | ((i >> 5) << 9) | (((i >> 3) & 3) << 7)
          | ((j & 15) << 3) | (i & 7);
    w2t[(size_t)p * H_ + k0 + kk] = (_Float16)tile[kk][n];
  }
}

// ---------------- h = relu(actions@w1+b1) fp16 [16384][256] ------------------
__global__ __launch_bounds__(256) void h_kernel(const float* __restrict__ actions,
                                                const float* __restrict__ w1,
                                                const float* __restrict__ b1,
                                                _Float16* __restrict__ h16) {
  __shared__ float w1s[32 * 256];
  __shared__ float acts[32 * 64];
  const int t = threadIdx.x;
  const size_t row0 = (size_t)blockIdx.x * 32;

  #pragma unroll
  for (int i = 0; i < 8; ++i) acts[t + i * 256] = actions[row0 * A_ + t + i * 256];

  float acc[32];
  float bj = b1[t];
  #pragma unroll
  for (int r = 0; r < 32; ++r) acc[r] = bj;

  for (int half = 0; half < 2; ++half) {
    __syncthreads();
    #pragma unroll
    for (int i = 0; i < 32; ++i) w1s[t + i * 256] = w1[half * 32 * 256 + t + i * 256];
    __syncthreads();
    #pragma unroll
    for (int r = 0; r < 32; ++r) {
      float a = acc[r];
      #pragma unroll
      for (int k = 0; k < 32; ++k)
        a += acts[r * 64 + half * 32 + k] * w1s[k * 256 + t];
      acc[r] = a;
    }
  }
  #pragma unroll
  for (int r = 0; r < 32; ++r)
    h16[(row0 + r) * H_ + t] = (_Float16)fmaxf(acc[r], 0.f);
}

// ---------------- fused: rec blocks 0..31, persistent gemm 32..255 -----------
__global__ __launch_bounds__(512, 2) void fused_kernel(
    const _Float16* __restrict__ h16, const _Float16* __restrict__ w2t,
    const float* __restrict__ b2, _Float16* __restrict__ tbuf0,
    _Float16* __restrict__ tbuf1, const float* __restrict__ init_s,
    float* __restrict__ out, float* __restrict__ dummyws,
    int Tc, int tcs, int c, int nch) {

  // layout: ring [0,49152) (8 waves x 2 slots x 3 KB), sb0 @49152 (256 B),
  // sb1 @49408, red[8] @49664. gemm branch uses [0,32768).
  __shared__ __align__(16) char smem[49920];
  const int tid  = threadIdx.x;
  const int lane = tid & 63;
  const int w    = tid >> 6;

  if (blockIdx.x < 32) {
    // ======================= recurrence block ===============================
    if (c < 0) return;
    const char* trans = (const char*)((c & 1) ? tbuf1 : tbuf0);
    const int b  = blockIdx.x;
    const int t0 = c * Tc;
    const int n16 = lane & 15, q = lane >> 4;
    const int col = w * 16 + n16;
    float* red = (float*)(smem + 49664);
    _Float16* sb0p = (_Float16*)(smem + 49152);

    // ---- init s_0 (normalized carry) into sb0 — plain C++, no DMAs yet ----
    float v0 = 0.f;
    if (tid < 128) {
      v0 = (t0 == 0) ? init_s[tid] : out[((size_t)b * T_ + t0 - 1) * D_ + tid];
      float ss = v0 * v0;
      #pragma unroll
      for (int off = 32; off > 0; off >>= 1) ss += __shfl_xor(ss, off);
      if (lane == 0) red[w] = ss;
    }
    __syncthreads();
    if (tid < 128) {
      float inv0 = 1.f / fmaxf(sqrtf(red[0] + red[1]), 1e-12f);
      sb0p[tid] = (_Float16)(v0 * inv0);
    }
    __syncthreads();

    float uprev = (float)sb0p[col];   // so chunk-boundary rewrite is a no-op

    // addresses
    const unsigned sbase = (unsigned)(size_t)(__attribute__((address_space(3))) char*)smem;
    const unsigned bq0 = sbase + w * 6144 + q * 256 + n16 * 16;
    const unsigned bq1 = bq0 + 3072;
    const unsigned aA0 = sbase + 49152 + q * 16;
    const unsigned aA1 = aA0 + 256;
    const unsigned aW0 = sbase + 49408 + col * 2;   // step par 0 writes sb1
    const unsigned aW1 = sbase + 49152 + col * 2;   // step par 1 writes sb0
    const char* Gw = trans + (size_t)b * Tc * 32768 + w * 4096 + lane * 16;
    float* outb = out + (size_t)b * T_ * D_ + col;
    float* dsink = dummyws + blockIdx.x * 128 + col;

    // ---- warmup: slots 0,1 (per wave: 3 DMA + 1 pinned reg load each) ----
    f16x8 r3[2];
    {
      const char* g0 = Gw;
      glds(g0,        smem + w * 6144);
      glds(g0 + 1024, smem + w * 6144 + 1024);
      glds(g0 + 2048, smem + w * 6144 + 2048);
      asm volatile("global_load_dwordx4 %0, %1, off"
                   : "=v"(r3[0]) : "v"(g0 + 3072) : "memory");
      const char* g1 = Gw + 32768;
      glds(g1,        smem + w * 6144 + 3072);
      glds(g1 + 1024, smem + w * 6144 + 3072 + 1024);
      glds(g1 + 2048, smem + w * 6144 + 3072 + 2048);
      asm volatile("global_load_dwordx4 %0, %1, off"
                   : "=v"(r3[1]) : "v"(g1 + 3072) : "memory");
    }

    const f32x4 zf = {0.f, 0.f, 0.f, 0.f};

#define STEP(TT, PAR, WAITN)                                                  \
    {                                                                         \
      const int tt = (TT);                                                    \
      f16x8 A0, A1, A2, A3, Bq0, Bq1, Bq2;                                    \
      asm volatile(                                                           \
        "s_waitcnt vmcnt(" #WAITN ")\n\t"                                     \
        "ds_read_b128 %0, %8 offset:0\n\t"                                    \
        "ds_read_b128 %1, %8 offset:64\n\t"                                   \
        "ds_read_b128 %2, %8 offset:128\n\t"                                  \
        "ds_read_b128 %3, %8 offset:192\n\t"                                  \
        "ds_read_b128 %4, %9 offset:0\n\t"                                    \
        "ds_read_b128 %5, %9 offset:1024\n\t"                                 \
        "ds_read_b128 %6, %9 offset:2048\n\t"                                 \
        "s_waitcnt lgkmcnt(0)"                                                \
        : "=v"(A0), "=v"(A1), "=v"(A2), "=v"(A3),                             \
          "=v"(Bq0), "=v"(Bq1), "=v"(Bq2), "+v"(r3[PAR])                      \
        : "v"(aA##PAR), "v"(bq##PAR) : "memory");                             \
      f32x4 c0 = __builtin_amdgcn_mfma_f32_16x16x32_f16(A0, Bq0, zf, 0, 0, 0);\
      f32x4 c1 = __builtin_amdgcn_mfma_f32_16x16x32_f16(A1, Bq1, zf, 0, 0, 0);\
      f32x4 c2 = __builtin_amdgcn_mfma_f32_16x16x32_f16(A2, Bq2, zf, 0, 0, 0);\
      f32x4 c3 = __builtin_amdgcn_mfma_f32_16x16x32_f16(A3, r3[PAR], zf, 0, 0, 0);\
      f32x4 cs = __builtin_amdgcn_mfma_f32_16x16x32_f16(A0, A0, zf, 0, 0, 0); \
      cs = __builtin_amdgcn_mfma_f32_16x16x32_f16(A1, A1, cs, 0, 0, 0);       \
      cs = __builtin_amdgcn_mfma_f32_16x16x32_f16(A2, A2, cs, 0, 0, 0);       \
      cs = __builtin_amdgcn_mfma_f32_16x16x32_f16(A3, A3, cs, 0, 0, 0);       \
      int nt = tt + 2; if (nt >= Tc) nt -= Tc;                                \
      const char* gd = Gw + (size_t)nt * 32768;                               \
      glds(gd,        smem + w * 6144 + (PAR) * 3072);                        \
      glds(gd + 1024, smem + w * 6144 + (PAR) * 3072 + 1024);                 \
      glds(gd + 2048, smem + w * 6144 + (PAR) * 3072 + 2048);                 \
      asm volatile("global_load_dwordx4 %0, %1, off"                          \
                   : "=v"(r3[PAR]) : "v"(gd + 3072) : "memory");              \
      float ssp = cs[0];                                                      \
      float inv = 1.f / fmaxf(sqrtf(ssp), 1e-12f);                            \
      float y = c0[0] + c1[0] + c2[0] + c3[0];                                \
      float un = fmaxf(y, 0.f) * inv;                                         \
      float o = uprev * inv;                                                  \
      uprev = un;                                                             \
      _Float16 hv = (_Float16)un;                                             \
      const int gt = t0 + tt;                                                 \
      float* gp = (gt > 0) ? (outb + (size_t)(gt - 1) * D_) : dsink;          \
      asm volatile("ds_write_b16 %0, %1\n\t"                                  \
                   "global_store_dword %2, %3, off"                           \
                   :: "v"(aW##PAR), "v"(hv), "v"(gp), "v"(o) : "memory");     \
      asm volatile("s_waitcnt lgkmcnt(0)\n\ts_barrier" ::: "memory");         \
    }

    STEP(0, 0, 4)
    STEP(1, 1, 5)
    for (int tt0 = 2; tt0 < Tc; tt0 += 2) {
      STEP(tt0, 0, 6)
      STEP(tt0 + 1, 1, 6)
    }
#undef STEP
    asm volatile("s_waitcnt vmcnt(0)" ::: "memory");

    // ---- epilogue: final norm (state in sb0; Tc even), write step Tc-1 ----
    {
      float x = 0.f;
      if (lane < 16) x = (float)((_Float16*)(smem + 49152))[col];
      float ss2 = x * x;
      ss2 += __shfl_xor(ss2, 1);
      ss2 += __shfl_xor(ss2, 2);
      ss2 += __shfl_xor(ss2, 4);
      ss2 += __shfl_xor(ss2, 8);
      if (lane == 0) red[w] = ss2;
      __syncthreads();
      float tot = 0.f;
      #pragma unroll
      for (int g = 0; g < 8; ++g) tot += red[g];
      float inv = 1.f / fmaxf(sqrtf(tot), 1e-12f);
      if (lane < 16) outb[(size_t)(t0 + Tc - 1) * D_] = uprev * inv;
    }
  } else {
    // ======================= persistent gemm (chunk c+1) ====================
    const int g = c + 1;
    if (g >= nch) return;
    _Float16* trans = (g & 1) ? tbuf1 : tbuf0;
    const int t0g = g * Tc;

    _Float16* smA = (_Float16*)smem;            // 256x32 fp16 = 16 KB
    _Float16* smB = (_Float16*)(smem + 16384);  // 16 KB

    const int wm = w >> 2, wn = w & 3;          // 2x4 wave grid: 128m x 64n
    const int fm = lane & 15, fq = lane >> 4;
    const f32x4 zero = {0.f, 0.f, 0.f, 0.f};

    const int cA0 = tid, cA1 = tid + 512;
    const int rA0 = cA0 >> 2, kA0 = cA0 & 3;
    const int rA1 = cA1 >> 2, kA1 = cA1 & 3;

    const int mtiles = (B_ * Tc) >> 8;
    const int ntot = mtiles * 64;
    for (int tile = (int)blockIdx.x - 32; tile < ntot; tile += 224) {
      const int bn = tile & 63;
      const int bm = tile >> 6;

      const int mc0 = bm * 256 + rA0, mc1 = bm * 256 + rA1;
      const int bb0 = mc0 >> tcs, bb1 = mc1 >> tcs;
      const _Float16* gA0 = h16 + ((size_t)bb0 * T_ + t0g + (mc0 & (Tc - 1))) * H_ + kA0 * 8;
      const _Float16* gA1 = h16 + ((size_t)bb1 * T_ + t0g + (mc1 & (Tc - 1))) * H_ + kA1 * 8;
      const _Float16* gB0 = w2t + ((size_t)bn * 256 + rA0) * H_ + kA0 * 8;
      const _Float16* gB1 = w2t + ((size_t)bn * 256 + rA1) * H_ + kA1 * 8;
      _Float16* lA0 = &smA[cA0 * 8];
      _Float16* lA1 = &smA[cA1 * 8];
      _Float16* lB0 = &smB[cA0 * 8];
      _Float16* lB1 = &smB[cA1 * 8];

      f32x4 acc[8][4];
      #pragma unroll
      for (int i = 0; i < 8; ++i)
        #pragma unroll
        for (int j = 0; j < 4; ++j) acc[i][j] = zero;

      for (int kt = 0; kt < H_ / 32; ++kt) {
        __syncthreads();
        glds(gA0 + kt * 32, lA0);
        glds(gA1 + kt * 32, lA1);
        glds(gB0 + kt * 32, lB0);
        glds(gB1 + kt * 32, lB1);
        __syncthreads();
        f16x8 af[8], bf[4];
        #pragma unroll
        for (int mt = 0; mt < 8; ++mt)
          af[mt] = *(const f16x8*)&smA[(wm * 128 + mt * 16 + fm) * 32 + fq * 8];
        #pragma unroll
        for (int nt = 0; nt < 4; ++nt)
          bf[nt] = *(const f16x8*)&smB[(wn * 64 + nt * 16 + fm) * 32 + fq * 8];
        #pragma unroll
        for (int mt = 0; mt < 8; ++mt)
          #pragma unroll
          for (int nt = 0; nt < 4; ++nt)
            acc[mt][nt] = __builtin_amdgcn_mfma_f32_16x16x32_f16(af[mt], bf[nt], acc[mt][nt], 0, 0, 0);
      }

      // epilogue: col is permuted p; invert for b2
      #pragma unroll
      for (int nt = 0; nt < 4; ++nt) {
        int col = bn * 256 + wn * 64 + nt * 16 + fm;
        int pw = col >> 11, pf = (col >> 9) & 3, pq = (col >> 7) & 3;
        int pn = (col >> 3) & 15, pr = col & 7;
        int ii = pf * 32 + pq * 8 + pr, jj = pw * 16 + pn;
        float bias = b2[ii * 128 + jj];
        #pragma unroll
        for (int mt = 0; mt < 8; ++mt) {
          #pragma unroll
          for (int r = 0; r < 4; ++r) {
            long row = bm * 256 + wm * 128 + mt * 16 + fq * 4 + r;
            trans[row * (long)N_ + col] = (_Float16)(acc[mt][nt][r] + bias);
          }
        }
      }
      __syncthreads();
    }
  }
}

// ---------------------------------------------------------------------------
extern "C" void kernel_launch(void* const* d_in, const int* in_sizes, int n_in,
                              void* d_out, int out_size, void* d_ws, size_t ws_size,
                              hipStream_t stream) {
  const float* actions = (const float*)d_in[0];   // [32,512,64]
  const float* init_s  = (const float*)d_in[1];   // [128]
  const float* w1      = (const float*)d_in[2];   // [64,256]
  const float* b1      = (const float*)d_in[3];   // [256]
  const float* w2      = (const float*)d_in[4];   // [256,16384]
  const float* b2      = (const float*)d_in[5];   // [16384]
  float* out = (float*)d_out;                     // [32,512,128]

  uint8_t* ws = (uint8_t*)d_ws;
  _Float16* w2t = (_Float16*)ws;                          // 8 MB (permuted rows)
  _Float16* h16 = (_Float16*)(ws + ((size_t)8 << 20));    // 8 MB
  const size_t trans_off = (size_t)16 << 20;

  // largest Tc whose double-buffered trans + 64KB sink fits
  int Tc = 16;
  const int cands[3] = {64, 32, 16};
  for (int i = 0; i < 3; ++i) {
    if (trans_off + 2 * ((size_t)cands[i] << 20) + 65536 <= ws_size) { Tc = cands[i]; break; }
  }
  const int tcs = __builtin_ctz(Tc);
  _Float16* tbuf0 = (_Float16*)(ws + trans_off);
  _Float16* tbuf1 = (_Float16*)(ws + trans_off + ((size_t)Tc << 20));
  float* dummyws = (float*)(ws + trans_off + 2 * ((size_t)Tc << 20));

  w2cast_kernel<<<dim3(N_ / 64, 4), 256, 0, stream>>>(w2, w2t);
  h_kernel<<<M_ / 32, 256, 0, stream>>>(actions, w1, b1, h16);

  const int nch = T_ / Tc;
  for (int c = -1; c < nch; ++c) {
    fused_kernel<<<256, 512, 0, stream>>>(
        h16, w2t, b2, tbuf0, tbuf1, init_s, out, dummyws, Tc, tcs, c, nch);
  }
}

// Round 8
// 522.655 us; speedup vs baseline: 5.7789x; 1.0030x over previous
//
#include <hip/hip_runtime.h>
#include <stdint.h>
#include <math.h>

// ---------------------------------------------------------------------------
// PathIntegration: h = relu(actions@w1+b1); trans = (h@w2+b2) -> [B,T,D,D]
// s_{t+1} = l2norm(relu(s_t @ trans_t)); output ys[B,T,D] (f32)
// B=32 T=512 A=64 H=256 D=128
// Round 8: rec streams T directly into a REGISTER ring (depth 4, 4x
// global_load_dwordx4/step/wave, 64 VGPRs pinned via asm ties) — the
// fragment-direct global layout makes per-lane addresses identical to the
// round-7 DMA+ds_read path, so correctness is preserved by construction.
// LDS per step: 4 ds_read_b128 (s broadcast) + 1 ds_write_b16 only.
// Manual vmcnt schedule (warmup 12,13,14,15; steady 16 — accounts for the
// 1 store/step in the queue). One s_barrier/step. ||s||^2 via MFMA(A,A).
// Grid = 256 exactly -> 1 block/CU -> no gemm/rec CU sharing.
// ---------------------------------------------------------------------------

typedef _Float16 f16x8 __attribute__((ext_vector_type(8)));
typedef float    f32x4 __attribute__((ext_vector_type(4)));

#define B_  32
#define T_  512
#define A_  64
#define H_  256
#define D_  128
#define N_  (D_ * D_)      // 16384
#define M_  (B_ * T_)      // 16384

__device__ inline void glds(const void* g, void* l) {
  __builtin_amdgcn_global_load_lds(
      (__attribute__((address_space(1))) void*)g,
      (__attribute__((address_space(3))) void*)l, 16, 0, 0);
}

// ---------------- w2 cast + transpose + fragment-direct PERMUTE --------------
// orig col n of w2 -> T entry (i=n>>7, j=n&127). New position (elements):
// p = (j>>4)<<11 | (i>>5)<<9 | ((i>>3)&3)<<7 | (j&15)<<3 | (i&7)
// so per (b,t) the 32 KB step-slab is wave-major, frag-major, lane-direct:
// byte ofs = w*4096 + f*1024 + lane*16 holds B-frag f of wave w.
__global__ __launch_bounds__(256) void w2cast_kernel(const float* __restrict__ w2,
                                                     _Float16* __restrict__ w2t) {
  __shared__ float tile[64][65];
  const int t = threadIdx.x;
  const int n0 = blockIdx.x * 64, k0 = blockIdx.y * 64;
  const int nn = t & 63, kg = t >> 6;
  #pragma unroll
  for (int r = 0; r < 16; ++r) {
    int k = kg * 16 + r;
    tile[k][nn] = w2[(size_t)(k0 + k) * N_ + n0 + nn];
  }
  __syncthreads();
  const int kk = t & 63, ng = t >> 6;
  #pragma unroll
  for (int r = 0; r < 16; ++r) {
    int n = ng * 16 + r;
    int ngl = n0 + n;
    int i = ngl >> 7, j = ngl & 127;
    int p = ((j >> 4) << 11) | ((i >> 5) << 9) | (((i >> 3) & 3) << 7)
          | ((j & 15) << 3) | (i & 7);
    w2t[(size_t)p * H_ + k0 + kk] = (_Float16)tile[kk][n];
  }
}

// ---------------- h = relu(actions@w1+b1) fp16 [16384][256] ------------------
__global__ __launch_bounds__(256) void h_kernel(const float* __restrict__ actions,
                                                const float* __restrict__ w1,
                                                const float* __restrict__ b1,
                                                _Float16* __restrict__ h16) {
  __shared__ float w1s[32 * 256];
  __shared__ float acts[32 * 64];
  const int t = threadIdx.x;
  const size_t row0 = (size_t)blockIdx.x * 32;

  #pragma unroll
  for (int i = 0; i < 8; ++i) acts[t + i * 256] = actions[row0 * A_ + t + i * 256];

  float acc[32];
  float bj = b1[t];
  #pragma unroll
  for (int r = 0; r < 32; ++r) acc[r] = bj;

  for (int half = 0; half < 2; ++half) {
    __syncthreads();
    #pragma unroll
    for (int i = 0; i < 32; ++i) w1s[t + i * 256] = w1[half * 32 * 256 + t + i * 256];
    __syncthreads();
    #pragma unroll
    for (int r = 0; r < 32; ++r) {
      float a = acc[r];
      #pragma unroll
      for (int k = 0; k < 32; ++k)
        a += acts[r * 64 + half * 32 + k] * w1s[k * 256 + t];
      acc[r] = a;
    }
  }
  #pragma unroll
  for (int r = 0; r < 32; ++r)
    h16[(row0 + r) * H_ + t] = (_Float16)fmaxf(acc[r], 0.f);
}

// ---------------- fused: rec blocks 0..31, persistent gemm 32..255 -----------
__global__ __launch_bounds__(512, 2) void fused_kernel(
    const _Float16* __restrict__ h16, const _Float16* __restrict__ w2t,
    const float* __restrict__ b2, _Float16* __restrict__ tbuf0,
    _Float16* __restrict__ tbuf1, const float* __restrict__ init_s,
    float* __restrict__ out, float* __restrict__ dummyws,
    int Tc, int tcs, int c, int nch) {

  // layout: gemm uses [0,32768). rec: sb0 @32768 (256B), sb1 @33024 (256B),
  // red @33280 (32B).
  __shared__ __align__(16) char smem[33536];
  const int tid  = threadIdx.x;
  const int lane = tid & 63;
  const int w    = tid >> 6;

  if (blockIdx.x < 32) {
    // ======================= recurrence block ===============================
    if (c < 0) return;
    const char* trans = (const char*)((c & 1) ? tbuf1 : tbuf0);
    const int b  = blockIdx.x;
    const int t0 = c * Tc;
    const int n16 = lane & 15, q = lane >> 4;
    const int col = w * 16 + n16;
    const int Tcm1 = Tc - 1;
    float* red = (float*)(smem + 33280);
    _Float16* sb0p = (_Float16*)(smem + 32768);

    // ---- init s_0 (normalized carry) into sb0 — plain C++, no asm yet ----
    float v0 = 0.f;
    if (tid < 128) {
      v0 = (t0 == 0) ? init_s[tid] : out[((size_t)b * T_ + t0 - 1) * D_ + tid];
      float ss = v0 * v0;
      #pragma unroll
      for (int off = 32; off > 0; off >>= 1) ss += __shfl_xor(ss, off);
      if (lane == 0) red[w] = ss;
    }
    __syncthreads();
    if (tid < 128) {
      float inv0 = 1.f / fmaxf(sqrtf(red[0] + red[1]), 1e-12f);
      sb0p[tid] = (_Float16)(v0 * inv0);
    }
    __syncthreads();

    float uprev = (float)sb0p[col];   // chunk-boundary rewrite is a no-op

    // addresses
    const unsigned sbase = (unsigned)(size_t)(__attribute__((address_space(3))) char*)smem;
    const unsigned aA0 = sbase + 32768 + q * 16;   // step par 0 reads sb0
    const unsigned aA1 = sbase + 33024 + q * 16;   // step par 1 reads sb1
    const unsigned aW0 = sbase + 33024 + col * 2;  // step par 0 writes sb1
    const unsigned aW1 = sbase + 32768 + col * 2;  // step par 1 writes sb0
    const char* Gw = trans + (size_t)b * Tc * 32768 + w * 4096 + lane * 16;
    float* outb = out + (size_t)b * T_ * D_ + col;
    float* dsink = dummyws + blockIdx.x * 128 + col;

    // ---- warmup: ring slots 0..3 <- slabs 0..3 (16 loads outstanding) ----
    f16x8 ring[4][4];
#define LDSLOT(S, P)                                                          \
    asm volatile("global_load_dwordx4 %0, %4, off\n\t"                        \
                 "global_load_dwordx4 %1, %4, off offset:1024\n\t"            \
                 "global_load_dwordx4 %2, %4, off offset:2048\n\t"            \
                 "global_load_dwordx4 %3, %4, off offset:3072"                \
                 : "=v"(ring[S][0]), "=v"(ring[S][1]),                        \
                   "=v"(ring[S][2]), "=v"(ring[S][3])                         \
                 : "v"(P) : "memory")
    LDSLOT(0, Gw + 0 * 32768);
    LDSLOT(1, Gw + 1 * 32768);
    LDSLOT(2, Gw + 2 * 32768);
    LDSLOT(3, Gw + 3 * 32768);

    const f32x4 zf = {0.f, 0.f, 0.f, 0.f};

#define STEP(TT, PAR, SPAR, WAITN)                                            \
    {                                                                         \
      const int tt = (TT);                                                    \
      f16x8 A0, A1, A2, A3;                                                   \
      asm volatile(                                                           \
        "s_waitcnt vmcnt(" #WAITN ")\n\t"                                     \
        "ds_read_b128 %0, %8 offset:0\n\t"                                    \
        "ds_read_b128 %1, %8 offset:64\n\t"                                   \
        "ds_read_b128 %2, %8 offset:128\n\t"                                  \
        "ds_read_b128 %3, %8 offset:192\n\t"                                  \
        "s_waitcnt lgkmcnt(0)"                                                \
        : "=v"(A0), "=v"(A1), "=v"(A2), "=v"(A3),                             \
          "+v"(ring[PAR][0]), "+v"(ring[PAR][1]),                             \
          "+v"(ring[PAR][2]), "+v"(ring[PAR][3])                              \
        : "v"(aA##SPAR) : "memory");                                          \
      f32x4 c0 = __builtin_amdgcn_mfma_f32_16x16x32_f16(A0, ring[PAR][0], zf, 0, 0, 0); \
      f32x4 c1 = __builtin_amdgcn_mfma_f32_16x16x32_f16(A1, ring[PAR][1], zf, 0, 0, 0); \
      f32x4 c2 = __builtin_amdgcn_mfma_f32_16x16x32_f16(A2, ring[PAR][2], zf, 0, 0, 0); \
      f32x4 c3 = __builtin_amdgcn_mfma_f32_16x16x32_f16(A3, ring[PAR][3], zf, 0, 0, 0); \
      f32x4 cs = __builtin_amdgcn_mfma_f32_16x16x32_f16(A0, A0, zf, 0, 0, 0); \
      cs = __builtin_amdgcn_mfma_f32_16x16x32_f16(A1, A1, cs, 0, 0, 0);       \
      cs = __builtin_amdgcn_mfma_f32_16x16x32_f16(A2, A2, cs, 0, 0, 0);       \
      cs = __builtin_amdgcn_mfma_f32_16x16x32_f16(A3, A3, cs, 0, 0, 0);       \
      const char* gd = Gw + (size_t)((tt + 4) & Tcm1) * 32768;                \
      LDSLOT(PAR, gd);                                                        \
      float ssp = cs[0];                                                      \
      float inv = 1.f / fmaxf(sqrtf(ssp), 1e-12f);                            \
      float y = c0[0] + c1[0] + c2[0] + c3[0];                                \
      float un = fmaxf(y, 0.f) * inv;                                         \
      float o = uprev * inv;                                                  \
      uprev = un;                                                             \
      _Float16 hv = (_Float16)un;                                             \
      const int gt = t0 + tt;                                                 \
      float* gp = (gt > 0) ? (outb + (size_t)(gt - 1) * D_) : dsink;          \
      asm volatile("ds_write_b16 %0, %1\n\t"                                  \
                   "global_store_dword %2, %3, off"                           \
                   :: "v"(aW##SPAR), "v"(hv), "v"(gp), "v"(o) : "memory");    \
      asm volatile("s_waitcnt lgkmcnt(0)\n\ts_barrier" ::: "memory");         \
    }

    STEP(0, 0, 0, 12)
    STEP(1, 1, 1, 13)
    STEP(2, 2, 0, 14)
    STEP(3, 3, 1, 15)
    for (int tt0 = 4; tt0 < Tc; tt0 += 4) {
      STEP(tt0,     0, 0, 16)
      STEP(tt0 + 1, 1, 1, 16)
      STEP(tt0 + 2, 2, 0, 16)
      STEP(tt0 + 3, 3, 1, 16)
    }
#undef STEP
#undef LDSLOT
    asm volatile("s_waitcnt vmcnt(0)" ::: "memory");

    // ---- epilogue: final norm (state in sb0; Tc mult of 4), write Tc-1 ----
    {
      float x = 0.f;
      if (lane < 16) x = (float)((_Float16*)(smem + 32768))[col];
      float ss2 = x * x;
      ss2 += __shfl_xor(ss2, 1);
      ss2 += __shfl_xor(ss2, 2);
      ss2 += __shfl_xor(ss2, 4);
      ss2 += __shfl_xor(ss2, 8);
      if (lane == 0) red[w] = ss2;
      __syncthreads();
      float tot = 0.f;
      #pragma unroll
      for (int g = 0; g < 8; ++g) tot += red[g];
      float inv = 1.f / fmaxf(sqrtf(tot), 1e-12f);
      if (lane < 16) outb[(size_t)(t0 + Tc - 1) * D_] = uprev * inv;
    }
  } else {
    // ======================= persistent gemm (chunk c+1) ====================
    const int g = c + 1;
    if (g >= nch) return;
    _Float16* trans = (g & 1) ? tbuf1 : tbuf0;
    const int t0g = g * Tc;

    _Float16* smA = (_Float16*)smem;            // 256x32 fp16 = 16 KB
    _Float16* smB = (_Float16*)(smem + 16384);  // 16 KB

    const int wm = w >> 2, wn = w & 3;          // 2x4 wave grid: 128m x 64n
    const int fm = lane & 15, fq = lane >> 4;
    const f32x4 zero = {0.f, 0.f, 0.f, 0.f};

    const int cA0 = tid, cA1 = tid + 512;
    const int rA0 = cA0 >> 2, kA0 = cA0 & 3;
    const int rA1 = cA1 >> 2, kA1 = cA1 & 3;

    const int mtiles = (B_ * Tc) >> 8;
    const int ntot = mtiles * 64;
    for (int tile = (int)blockIdx.x - 32; tile < ntot; tile += 224) {
      const int bn = tile & 63;
      const int bm = tile >> 6;

      const int mc0 = bm * 256 + rA0, mc1 = bm * 256 + rA1;
      const int bb0 = mc0 >> tcs, bb1 = mc1 >> tcs;
      const _Float16* gA0 = h16 + ((size_t)bb0 * T_ + t0g + (mc0 & (Tc - 1))) * H_ + kA0 * 8;
      const _Float16* gA1 = h16 + ((size_t)bb1 * T_ + t0g + (mc1 & (Tc - 1))) * H_ + kA1 * 8;
      const _Float16* gB0 = w2t + ((size_t)bn * 256 + rA0) * H_ + kA0 * 8;
      const _Float16* gB1 = w2t + ((size_t)bn * 256 + rA1) * H_ + kA1 * 8;
      _Float16* lA0 = &smA[cA0 * 8];
      _Float16* lA1 = &smA[cA1 * 8];
      _Float16* lB0 = &smB[cA0 * 8];
      _Float16* lB1 = &smB[cA1 * 8];

      f32x4 acc[8][4];
      #pragma unroll
      for (int i = 0; i < 8; ++i)
        #pragma unroll
        for (int j = 0; j < 4; ++j) acc[i][j] = zero;

      for (int kt = 0; kt < H_ / 32; ++kt) {
        __syncthreads();
        glds(gA0 + kt * 32, lA0);
        glds(gA1 + kt * 32, lA1);
        glds(gB0 + kt * 32, lB0);
        glds(gB1 + kt * 32, lB1);
        __syncthreads();
        f16x8 af[8], bf[4];
        #pragma unroll
        for (int mt = 0; mt < 8; ++mt)
          af[mt] = *(const f16x8*)&smA[(wm * 128 + mt * 16 + fm) * 32 + fq * 8];
        #pragma unroll
        for (int nt = 0; nt < 4; ++nt)
          bf[nt] = *(const f16x8*)&smB[(wn * 64 + nt * 16 + fm) * 32 + fq * 8];
        #pragma unroll
        for (int mt = 0; mt < 8; ++mt)
          #pragma unroll
          for (int nt = 0; nt < 4; ++nt)
            acc[mt][nt] = __builtin_amdgcn_mfma_f32_16x16x32_f16(af[mt], bf[nt], acc[mt][nt], 0, 0, 0);
      }

      // epilogue: col is permuted p; invert for b2
      #pragma unroll
      for (int nt = 0; nt < 4; ++nt) {
        int col = bn * 256 + wn * 64 + nt * 16 + fm;
        int pw = col >> 11, pf = (col >> 9) & 3, pq = (col >> 7) & 3;
        int pn = (col >> 3) & 15, pr = col & 7;
        int ii = pf * 32 + pq * 8 + pr, jj = pw * 16 + pn;
        float bias = b2[ii * 128 + jj];
        #pragma unroll
        for (int mt = 0; mt < 8; ++mt) {
          #pragma unroll
          for (int r = 0; r < 4; ++r) {
            long row = bm * 256 + wm * 128 + mt * 16 + fq * 4 + r;
            trans[row * (long)N_ + col] = (_Float16)(acc[mt][nt][r] + bias);
          }
        }
      }
      __syncthreads();
    }
  }
}

// ---------------------------------------------------------------------------
extern "C" void kernel_launch(void* const* d_in, const int* in_sizes, int n_in,
                              void* d_out, int out_size, void* d_ws, size_t ws_size,
                              hipStream_t stream) {
  const float* actions = (const float*)d_in[0];   // [32,512,64]
  const float* init_s  = (const float*)d_in[1];   // [128]
  const float* w1      = (const float*)d_in[2];   // [64,256]
  const float* b1      = (const float*)d_in[3];   // [256]
  const float* w2      = (const float*)d_in[4];   // [256,16384]
  const float* b2      = (const float*)d_in[5];   // [16384]
  float* out = (float*)d_out;                     // [32,512,128]

  uint8_t* ws = (uint8_t*)d_ws;
  _Float16* w2t = (_Float16*)ws;                          // 8 MB (permuted rows)
  _Float16* h16 = (_Float16*)(ws + ((size_t)8 << 20));    // 8 MB
  const size_t trans_off = (size_t)16 << 20;

  // largest Tc whose double-buffered trans + 64KB sink fits
  int Tc = 16;
  const int cands[3] = {64, 32, 16};
  for (int i = 0; i < 3; ++i) {
    if (trans_off + 2 * ((size_t)cands[i] << 20) + 65536 <= ws_size) { Tc = cands[i]; break; }
  }
  const int tcs = __builtin_ctz(Tc);
  _Float16* tbuf0 = (_Float16*)(ws + trans_off);
  _Float16* tbuf1 = (_Float16*)(ws + trans_off + ((size_t)Tc << 20));
  float* dummyws = (float*)(ws + trans_off + 2 * ((size_t)Tc << 20));

  w2cast_kernel<<<dim3(N_ / 64, 4), 256, 0, stream>>>(w2, w2t);
  h_kernel<<<M_ / 32, 256, 0, stream>>>(actions, w1, b1, h16);

  const int nch = T_ / Tc;
  for (int c = -1; c < nch; ++c) {
    fused_kernel<<<256, 512, 0, stream>>>(
        h16, w2t, b2, tbuf0, tbuf1, init_s, out, dummyws, Tc, tcs, c, nch);
  }
}